// Round 1
// baseline (532.221 us; speedup 1.0000x reference)
//
#include <hip/hip_runtime.h>
#include <cstdint>
#include <cstddef>

#define NNODES 100000
#define NEDGES 1600000
#define DIM 128
#define NREL 8
#define NSEG (NNODES * NREL)                       // 800,000 segments
#define SCAN_BLK 2048
#define NSCAN ((NSEG + SCAN_BLK - 1) / SCAN_BLK)   // 391 scan blocks
#define NKT 36                                     // 1152 / 32 K-steps
#define A16ROW 1160                                // f16 LDS row stride (ushorts)
#define CVT4 (NNODES * DIM / 4)                    // 3,200,000 float4 groups

typedef float f32x4 __attribute__((ext_vector_type(4)));
typedef short short8 __attribute__((ext_vector_type(8)));
typedef _Float16 half8 __attribute__((ext_vector_type(8)));

__device__ inline float h2f(unsigned short u) {
    return (float)__builtin_bit_cast(_Float16, u);
}
__device__ inline unsigned short f2h(float f) {
    return __builtin_bit_cast(unsigned short, (_Float16)f);
}

// ------------------------------------------------- count + cvt (fused) ----
__global__ __launch_bounds__(256) void count_cvt(const int* __restrict__ dst,
                                                 const int* __restrict__ et,
                                                 int* __restrict__ cnt,
                                                 const float* __restrict__ x,
                                                 unsigned short* __restrict__ xh) {
    int gid = blockIdx.x * 256 + threadIdx.x;
    if (gid < NEDGES) atomicAdd(&cnt[dst[gid] * NREL + et[gid]], 1);
    if (gid < CVT4) {
        float4 v = *(const float4*)(x + (size_t)gid * 4);
        ushort4 o = make_ushort4(f2h(v.x), f2h(v.y), f2h(v.z), f2h(v.w));
        *(ushort4*)(xh + (size_t)gid * 4) = o;
    }
}

// ------------------------------------------------- scan pass1 (+inv fuse) ---
__global__ __launch_bounds__(256) void scan_pass1(const int* __restrict__ cnt,
                                                  int* __restrict__ bsum,
                                                  float* __restrict__ inv) {
    int base = blockIdx.x * SCAN_BLK + threadIdx.x * 8;
    int s = 0;
#pragma unroll
    for (int j = 0; j < 8; ++j) {
        int i = base + j;
        if (i < NSEG) {
            int c = cnt[i];
            s += c;
            inv[i] = 1.0f / (float)(c > 1 ? c : 1);
        }
    }
    __shared__ int ws[4];
    for (int d = 1; d < 64; d <<= 1) s += __shfl_xor(s, d);
    int lane = threadIdx.x & 63, w = threadIdx.x >> 6;
    if (lane == 0) ws[w] = s;
    __syncthreads();
    if (threadIdx.x == 0) bsum[blockIdx.x] = ws[0] + ws[1] + ws[2] + ws[3];
}

__global__ __launch_bounds__(64) void scan_pass2(int* __restrict__ bsum) {
    int lane = threadIdx.x;
    int vals[7];
    int s = 0;
#pragma unroll
    for (int j = 0; j < 7; ++j) {
        int i = lane * 7 + j;
        vals[j] = (i < NSCAN) ? bsum[i] : 0;
        s += vals[j];
    }
    int incl = s;
    for (int d = 1; d < 64; d <<= 1) {
        int u = __shfl_up(incl, d);
        if (lane >= d) incl += u;
    }
    int base = incl - s;
#pragma unroll
    for (int j = 0; j < 7; ++j) {
        int i = lane * 7 + j;
        if (i < NSCAN) bsum[i] = base;
        base += vals[j];
    }
}

__global__ __launch_bounds__(256) void scan_pass3(const int* __restrict__ cnt,
                                                  const int* __restrict__ bsum,
                                                  int* __restrict__ segend) {
    int tid = threadIdx.x;
    int base = blockIdx.x * SCAN_BLK + tid * 8;
    int v[8];
    int s = 0;
#pragma unroll
    for (int j = 0; j < 8; ++j) {
        int i = base + j;
        v[j] = (i < NSEG) ? cnt[i] : 0;
        s += v[j];
    }
    int lane = tid & 63, w = tid >> 6;
    int incl = s;
    for (int d = 1; d < 64; d <<= 1) {
        int u = __shfl_up(incl, d);
        if (lane >= d) incl += u;
    }
    __shared__ int wtot[4];
    if (lane == 63) wtot[w] = incl;
    __syncthreads();
    int wbase = 0;
#pragma unroll
    for (int k = 0; k < 4; ++k)
        if (k < w) wbase += wtot[k];
    int tbase = bsum[blockIdx.x] + wbase + (incl - s);
#pragma unroll
    for (int j = 0; j < 8; ++j) {
        int i = base + j;
        if (i < NSEG) segend[i] = tbase;   // becomes segment END after bucketing
        tbase += v[j];
    }
}

// --------------------------------------------------------------- bucket ----
// einfo[p] = src | (rel << 20)   (src < 2^20). inv applied at flush time now.
__global__ __launch_bounds__(256) void bucket_kernel(const int* __restrict__ src,
                                                     const int* __restrict__ dst,
                                                     const int* __restrict__ et,
                                                     int* __restrict__ segend,
                                                     int* __restrict__ einfo) {
    int e = blockIdx.x * 256 + threadIdx.x;
    if (e >= NEDGES) return;
    int seg = dst[e] * NREL + et[e];
    int p = atomicAdd(&segend[seg], 1);
    einfo[p] = src[e] | ((seg & 7) << 20);
}

// ----------------------------------------------------- pack W into B-frags --
__global__ __launch_bounds__(64) void pack_w2(const float* __restrict__ Wrel1,
                                              const float* __restrict__ Wroot1,
                                              const float* __restrict__ Wrel2,
                                              const float* __restrict__ Wroot2,
                                              unsigned short* __restrict__ Wp1,
                                              unsigned short* __restrict__ Wp2) {
    int bb = blockIdx.x;
    const float* Wrel = Wrel1;
    const float* Wroot = Wroot1;
    unsigned short* Wp = Wp1;
    if (bb >= NKT * 8) {
        bb -= NKT * 8;
        Wrel = Wrel2; Wroot = Wroot2; Wp = Wp2;
    }
    const int kt = bb >> 3, ht = bb & 7;
    const int lane = threadIdx.x;
    const int col = ht * 16 + (lane & 15);
    const int kbase = kt * 32 + (lane >> 4) * 8;
    unsigned short vals[8];
#pragma unroll
    for (int j = 0; j < 8; ++j) {
        int k = kbase + j;
        float f = (k < 1024) ? Wrel[(size_t)k * 128 + col]
                             : Wroot[(size_t)(k - 1024) * 128 + col];
        vals[j] = f2h(f);
    }
    unsigned short* dstp = Wp + ((size_t)bb * 64 + lane) * 8;
#pragma unroll
    for (int j = 0; j < 8; ++j) dstp[j] = vals[j];
}

// ---------------------------------------------------------- fused layer ----
// 16 nodes/block, 256 threads, 16 lanes/node.
// - per-group zero of EMPTY relation rows only (no blanket zero, no barrier)
// - 2-chunk-deep (16-edge) ping-pong gather pipeline, guarded prefetch
// - inv applied once per flush via __shfl from preloaded per-rel values
// - optional fused head (dot(out_w) + sigmoid) replaces final_kernel
#define GATHER_LOAD(Q, V, BASE)                                                \
    _Pragma("unroll")                                                          \
    for (int u = 0; u < 8; ++u) {                                              \
        int p = (BASE) + u;                                                    \
        Q[u] = einfo[p < last ? p : last];                                     \
    }                                                                          \
    _Pragma("unroll")                                                          \
    for (int u = 0; u < 8; ++u)                                                \
        V[u] = *(const short8*)(feat + (size_t)(Q[u] & 0xFFFFF) * DIM + l16 * 8);

#define GATHER_COMPUTE(Q, V)                                                   \
    _Pragma("unroll")                                                          \
    for (int u = 0; u < 8; ++u) {                                              \
        if (e + u < end) {                                                     \
            int s = ((unsigned)Q[u]) >> 20;                                    \
            if (s != cur) {                                                    \
                float sc = __shfl(invv, cur, 16);                              \
                short8 o;                                                      \
                _Pragma("unroll")                                              \
                for (int j = 0; j < 8; ++j) o[j] = (short)f2h(acc[j] * sc);    \
                *(short8*)(Arow + cur * DIM + l16 * 8) = o;                    \
                _Pragma("unroll")                                              \
                for (int j = 0; j < 8; ++j) acc[j] = 0.f;                      \
                cur = s;                                                       \
            }                                                                  \
            const short8 ve = V[u];                                            \
            _Pragma("unroll")                                                  \
            for (int j = 0; j < 8; ++j)                                        \
                acc[j] += h2f((unsigned short)ve[j]);                          \
        }                                                                      \
    }

__global__ __launch_bounds__(256, 4) void fused_layer(
    const unsigned short* __restrict__ feat,   // f16 [N][128]
    const int* __restrict__ segend,
    const int* __restrict__ einfo,
    const unsigned short* __restrict__ Wp,     // packed f16 B-frags
    const float* __restrict__ bias,
    const float* __restrict__ inv,
    unsigned short* __restrict__ out,          // f16 [N][128] (ignored in head mode)
    const float* __restrict__ outw,            // non-null => head mode
    const float* __restrict__ outb,
    float* __restrict__ head_out) {
    __shared__ __align__(16) unsigned short A16[16 * A16ROW + 8];
    const int tid = threadIdx.x;
    const int blk = blockIdx.x;
    const int g = tid >> 4, l16 = tid & 15;

    // root rows (each thread owns a disjoint 16B slice)
    *(short8*)(&A16[g * A16ROW + 1024 + l16 * 8]) =
        *(const short8*)(feat + ((size_t)blk * 16 + g) * DIM + l16 * 8);

    // segment bounds + per-relation inv for this node
    const int n = blk * 16 + g;
    const int segbase = n * NREL;
    const int se = segend[segbase + (l16 & 7)];
    const float invv = inv[segbase + (l16 & 7)];
    int prev = 0;
    if (l16 == 0) prev = (segbase == 0) ? 0 : segend[segbase - 1];
    prev = __shfl(prev, 0, 16);
    const int beg = prev;
    const int end = __shfl(se, 7, 16);

    unsigned short* Arow = &A16[g * A16ROW];

    // zero only the EMPTY relation rows of this group
    {
        int b = prev;
#pragma unroll
        for (int r = 0; r < 8; ++r) {
            int er = __shfl(se, r, 16);
            if (er == b) {
                short8 z = {0, 0, 0, 0, 0, 0, 0, 0};
                *(short8*)(Arow + r * DIM + l16 * 8) = z;
            }
            b = er;
        }
    }

    // ---- phase 1: 2-deep ping-pong gather pipeline ----
    if (beg < end) {
        const int last = end - 1;
        int q0[8], q1[8];
        short8 v0[8], v1[8];
        GATHER_LOAD(q0, v0, beg)
        if (beg + 8 < end) {
            GATHER_LOAD(q1, v1, beg + 8)
        }
        float acc[8] = {0.f, 0.f, 0.f, 0.f, 0.f, 0.f, 0.f, 0.f};
        int cur = ((unsigned)q0[0]) >> 20;
        int e = beg;
        while (true) {
            GATHER_COMPUTE(q0, v0)
            if (e + 8 >= end) break;
            if (e + 16 < end) {
                GATHER_LOAD(q0, v0, e + 16)
            }
            e += 8;
            GATHER_COMPUTE(q1, v1)
            if (e + 8 >= end) break;
            if (e + 16 < end) {
                GATHER_LOAD(q1, v1, e + 16)
            }
            e += 8;
        }
        // final flush
        float sc = __shfl(invv, cur, 16);
        short8 o;
#pragma unroll
        for (int j = 0; j < 8; ++j) o[j] = (short)f2h(acc[j] * sc);
        *(short8*)(Arow + cur * DIM + l16 * 8) = o;
    }
    __syncthreads();

    // ---- phase 2: MFMA ----
    const int lane = tid & 63;
    const int w = tid >> 6;                 // wave id -> h-tiles 2w, 2w+1
    const int m = lane & 15, kq = lane >> 4;
    const unsigned short* arow = &A16[m * A16ROW + kq * 8];
    f32x4 acc0 = {0.f, 0.f, 0.f, 0.f};
    f32x4 acc1 = {0.f, 0.f, 0.f, 0.f};

#pragma unroll 4
    for (int kt = 0; kt < NKT; ++kt) {
        short8 a = *(const short8*)(arow + kt * 32);
        short8 b0 = *(const short8*)(Wp + ((size_t)(kt * 8 + 2 * w) * 64 + lane) * 8);
        short8 b1 = *(const short8*)(Wp + ((size_t)(kt * 8 + 2 * w + 1) * 64 + lane) * 8);
        acc0 = __builtin_amdgcn_mfma_f32_16x16x32_f16(
            __builtin_bit_cast(half8, a), __builtin_bit_cast(half8, b0), acc0, 0, 0, 0);
        acc1 = __builtin_amdgcn_mfma_f32_16x16x32_f16(
            __builtin_bit_cast(half8, a), __builtin_bit_cast(half8, b1), acc1, 0, 0, 0);
    }

    // ---- epilogue (C/D: col=lane&15, row=quad*4+r) ----
    const int col = lane & 15;
    const int rbase = kq * 4;
    const int h0 = 32 * w + col;
    const int h1 = h0 + 16;
    const float bv0 = bias[h0], bv1 = bias[h1];

    if (!head_out) {
        // layer 1: bias + relu + f16 store
#pragma unroll
        for (int r = 0; r < 4; ++r) {
            const size_t nrow = ((size_t)blk * 16 + rbase + r) * DIM;
            out[nrow + h0] = f2h(fmaxf(acc0[r] + bv0, 0.f));
            out[nrow + h1] = f2h(fmaxf(acc1[r] + bv1, 0.f));
        }
    } else {
        // layer 2 + head: relu'd h dot out_w, reduce, sigmoid (no h2 roundtrip)
        const float w0 = outw[h0], w1 = outw[h1];
        float part[4];
#pragma unroll
        for (int r = 0; r < 4; ++r) {
            part[r] = fmaxf(acc0[r] + bv0, 0.f) * w0 + fmaxf(acc1[r] + bv1, 0.f) * w1;
#pragma unroll
            for (int d = 1; d < 16; d <<= 1)
                part[r] += __shfl_xor(part[r], d, 16);   // sum over 16 col-lanes
        }
        __syncthreads();                 // all A16 reads done; reuse LDS
        float* hp = (float*)A16;         // hp[node_local][wave]
        if (col == 0) {
#pragma unroll
            for (int r = 0; r < 4; ++r) hp[(kq * 4 + r) * 4 + w] = part[r];
        }
        __syncthreads();
        if (tid < 16) {
            float vsum = hp[tid * 4 + 0] + hp[tid * 4 + 1] +
                         hp[tid * 4 + 2] + hp[tid * 4 + 3] + outb[0];
            head_out[blk * 16 + tid] = 1.0f / (1.0f + __expf(-vsum));
        }
    }
}

// ---------------------------------------------------------------- launch ----
extern "C" void kernel_launch(void* const* d_in, const int* in_sizes, int n_in,
                              void* d_out, int out_size, void* d_ws, size_t ws_size,
                              hipStream_t stream) {
    const float* x      = (const float*)d_in[0];
    const int*   ei     = (const int*)d_in[1];
    const int*   et     = (const int*)d_in[2];
    const float* Wrel1  = (const float*)d_in[3];
    const float* Wroot1 = (const float*)d_in[4];
    const float* b1     = (const float*)d_in[5];
    const float* Wrel2  = (const float*)d_in[6];
    const float* Wroot2 = (const float*)d_in[7];
    const float* b2     = (const float*)d_in[8];
    const float* outw   = (const float*)d_in[9];
    const float* outb   = (const float*)d_in[10];
    const int* src = ei;
    const int* dst = ei + NEDGES;

    // workspace layout (~68 MB, 16B-aligned chunks)
    char* ws = (char*)d_ws;
    int*            cnt    = (int*)(ws + 0);                     //  3,200,000
    int*            bsum   = (int*)(ws + 3200000);               //      4,096
    int*            segend = (int*)(ws + 3204096);               //  3,200,000
    int*            einfo  = (int*)(ws + 6404096);               //  6,400,000
    unsigned short* xh     = (unsigned short*)(ws + 12804096);   // 25,600,000
    unsigned short* h1     = (unsigned short*)(ws + 38404096);   // 25,600,000
    unsigned short* Wp1    = (unsigned short*)(ws + 64004096);   //    294,912
    unsigned short* Wp2    = (unsigned short*)(ws + 64299008);   //    294,912
    float*          inv    = (float*)(ws + 64593920);            //  3,200,000
    // end: 67,793,920 B

    hipMemsetAsync(cnt, 0, (size_t)NSEG * 4, stream);
    count_cvt<<<(CVT4 + 255) / 256, 256, 0, stream>>>(dst, et, cnt, x, xh);
    scan_pass1<<<NSCAN, 256, 0, stream>>>(cnt, bsum, inv);
    scan_pass2<<<1, 64, 0, stream>>>(bsum);
    scan_pass3<<<NSCAN, 256, 0, stream>>>(cnt, bsum, segend);
    bucket_kernel<<<(NEDGES + 255) / 256, 256, 0, stream>>>(src, dst, et, segend, einfo);
    pack_w2<<<NKT * 8 * 2, 64, 0, stream>>>(Wrel1, Wroot1, Wrel2, Wroot2, Wp1, Wp2);

    fused_layer<<<NNODES / 16, 256, 0, stream>>>(xh, segend, einfo, Wp1, b1, inv,
                                                 h1, nullptr, nullptr, nullptr);
    fused_layer<<<NNODES / 16, 256, 0, stream>>>(h1, segend, einfo, Wp2, b2, inv,
                                                 nullptr, outw, outb, (float*)d_out);
}